// Round 5
// baseline (86.433 us; speedup 1.0000x reference)
//
#include <hip/hip_runtime.h>
#include <hip/hip_bf16.h>

typedef __attribute__((ext_vector_type(4))) float f32x4;
typedef __attribute__((ext_vector_type(8))) short bf16x8;
typedef __attribute__((ext_vector_type(16))) float f32x16;

#define MSZ 8192
#define D_DIM 256
#define BM 128
#define BN 128
#define BK 64
#define NT (D_DIM / BK)   // 4 K-tiles

#define GLOAD_LDS(g, s) __builtin_amdgcn_global_load_lds( \
    (const __attribute__((address_space(1))) unsigned int*)(g), \
    (__attribute__((address_space(3))) unsigned int*)(s), 16, 0, 0)

__device__ __forceinline__ unsigned short f2bf(float f) {
  __hip_bfloat16 h = __float2bfloat16(f);
  unsigned short u; __builtin_memcpy(&u, &h, 2); return u;
}

// ---------------- pass 1: fp32 -> bf16 copies + row norms into d_ws ----------------
__global__ __launch_bounds__(256)
void prep_kernel(const float* __restrict__ X, const float* __restrict__ Y,
                 unsigned short* __restrict__ Xb, unsigned short* __restrict__ Yb,
                 float* __restrict__ x2, float* __restrict__ y2) {
  int gw = (blockIdx.x * 256 + threadIdx.x) >> 6;   // one wave per row
  int l = threadIdx.x & 63;
  if (gw >= 2 * MSZ) return;
  int row = gw & (MSZ - 1);
  const float* src = (gw < MSZ ? X : Y) + (size_t)row * D_DIM + l * 4;
  f32x4 v = *(const f32x4*)src;
  float ss = v[0]*v[0] + v[1]*v[1] + v[2]*v[2] + v[3]*v[3];
  ushort4 o;
  o.x = f2bf(v[0]); o.y = f2bf(v[1]); o.z = f2bf(v[2]); o.w = f2bf(v[3]);
  unsigned short* dst = (gw < MSZ ? Xb : Yb) + (size_t)row * D_DIM + l * 4;
  *(ushort4*)dst = o;
  #pragma unroll
  for (int m = 1; m < 64; m <<= 1) ss += __shfl_xor(ss, m);
  if (l == 0) (gw < MSZ ? x2 : y2)[row] = ss;
}

// ------- pass 2: single-buffer bf16 MFMA (32x32), 4 blocks/CU, f32x4 stores -------
__global__ __launch_bounds__(256, 4)
void rbf_main(const unsigned short* __restrict__ Xb, const unsigned short* __restrict__ Yb,
              const float* __restrict__ X2, const float* __restrict__ Y2,
              float* __restrict__ Out) {
  __shared__ __align__(16) unsigned char smem[2 * 16384];   // A(16K)+B(16K), single buffer
  __shared__ float sx2[BM];

  int bid = blockIdx.x;
  int cpx = gridDim.x >> 3;             // 4096 % 8 == 0 -> bijective XCD swizzle
  int swz = (bid & 7) * cpx + (bid >> 3);
  int bm = swz >> 6;
  int bn = swz & 63;
  int rowBase = bm * BM, colBase = bn * BN;

  int tid = threadIdx.x;
  int l = tid & 63;
  int w = tid >> 6;          // 4 waves, 2x2 grid of 64x64 output sub-tiles
  int wr = w >> 1, wc = w & 1;

  if (tid < BM) sx2[tid] = X2[rowBase + tid];
  float sy0 = Y2[colBase + wc * 64 + (l & 31)];
  float sy1 = Y2[colBase + wc * 64 + 32 + (l & 31)];

  f32x16 acc[2][2] = {};

  unsigned char* As = smem;
  unsigned char* Bs = smem + 16384;

  // stage: wave w DMAs rows [w*32, w*32+32); LDS dest linear (gload_lds reqmt),
  // XOR swizzle applied on the GLOBAL source column (m173 pattern)
  #define STAGE(t)                                                                 \
    _Pragma("unroll")                                                              \
    for (int q = 0; q < 4; ++q) {                                                  \
      int row = w * 32 + q * 8 + (l >> 3);                                         \
      int gcol = (t) * BK + (((l & 7) ^ (row & 7)) << 3);                          \
      GLOAD_LDS(Xb + (size_t)(rowBase + row) * D_DIM + gcol, As + (w*32 + q*8) * 128); \
      GLOAD_LDS(Yb + (size_t)(colBase + row) * D_DIM + gcol, Bs + (w*32 + q*8) * 128); \
    }

  #define COMPUTE()                                                                \
    _Pragma("unroll")                                                              \
    for (int kk = 0; kk < 4; ++kk) {                                               \
      bf16x8 af[2], bfv[2];                                                        \
      _Pragma("unroll")                                                            \
      for (int i = 0; i < 2; ++i) {                                                \
        int ra = wr * 64 + i * 32 + (l & 31);                                      \
        int offa = ra * 128 + (((kk * 2 + (l >> 5)) << 4) ^ ((ra & 7) << 4));      \
        af[i] = *(bf16x8*)(As + offa);                                             \
        int rb = wc * 64 + i * 32 + (l & 31);                                      \
        int offb = rb * 128 + (((kk * 2 + (l >> 5)) << 4) ^ ((rb & 7) << 4));      \
        bfv[i] = *(bf16x8*)(Bs + offb);                                            \
      }                                                                            \
      _Pragma("unroll")                                                            \
      for (int i = 0; i < 2; ++i)                                                  \
        _Pragma("unroll")                                                          \
        for (int j = 0; j < 2; ++j)                                                \
          acc[i][j] = __builtin_amdgcn_mfma_f32_32x32x16_bf16(af[i], bfv[j], acc[i][j], 0, 0, 0); \
    }

  STAGE(0)
  #pragma unroll
  for (int t = 0; t < NT; ++t) {
    __syncthreads();                 // vmcnt(0)+lgkmcnt(0)+barrier: tile t visible
    COMPUTE()
    if (t + 1 < NT) {
      __syncthreads();               // all reads of tile t done before overwrite
      STAGE(t + 1)
    }
  }

  // ---- epilogue: exp, then in-register 4x4 transpose -> f32x4 full-line stores ----
  // C/D layout: col = l&31, row = (q&3) + 8*(q>>2) + 4*(l>>5)   [m74/m101]
  // After xor-butterfly transpose within lane quads, lane (4k+j) of each half-wave
  // holds row r0+j, cols 4k..4k+3 -> 16B/lane, 8 fully-covered 128B lines per store.
  int h4 = (l >> 5) * 4;     // half-wave row offset
  int kq = (l & 31) >> 2;    // quad within half-wave
  #pragma unroll
  for (int i = 0; i < 2; ++i) {
    #pragma unroll
    for (int j = 0; j < 2; ++j) {
      float sy = j ? sy1 : sy0;
      #pragma unroll
      for (int g = 0; g < 4; ++g) {
        int rb0 = wr * 64 + i * 32 + g * 8 + h4;     // rows rb0..rb0+3, e = q&3
        float p0, p1, p2, p3;
        {
          float sx0 = sx2[rb0 + 0], sx1 = sx2[rb0 + 1];
          float sx2v = sx2[rb0 + 2], sx3 = sx2[rb0 + 3];
          p0 = __expf(-fmaxf(fmaf(-2.0f, acc[i][j][g * 4 + 0], sx0 + sy), 0.0f));
          p1 = __expf(-fmaxf(fmaf(-2.0f, acc[i][j][g * 4 + 1], sx1 + sy), 0.0f));
          p2 = __expf(-fmaxf(fmaf(-2.0f, acc[i][j][g * 4 + 2], sx2v + sy), 0.0f));
          p3 = __expf(-fmaxf(fmaf(-2.0f, acc[i][j][g * 4 + 3], sx3 + sy), 0.0f));
        }
        // 4x4 transpose among lane quads: stage 1 (xor 1), pairs (p0,p1),(p2,p3)
        {
          float s01 = (l & 1) ? p0 : p1;
          float r01 = __shfl_xor(s01, 1);
          if (l & 1) p0 = r01; else p1 = r01;
          float s23 = (l & 1) ? p2 : p3;
          float r23 = __shfl_xor(s23, 1);
          if (l & 1) p2 = r23; else p3 = r23;
          // stage 2 (xor 2), pairs (p0,p2),(p1,p3)
          float s02 = (l & 2) ? p0 : p2;
          float r02 = __shfl_xor(s02, 2);
          if (l & 2) p0 = r02; else p2 = r02;
          float s13 = (l & 2) ? p1 : p3;
          float r13 = __shfl_xor(s13, 2);
          if (l & 2) p1 = r13; else p3 = r13;
        }
        int rowS = rowBase + rb0 + (l & 3);
        int colS = colBase + wc * 64 + j * 32 + kq * 4;
        f32x4 v; v[0] = p0; v[1] = p1; v[2] = p2; v[3] = p3;
        *(f32x4*)(Out + (size_t)rowS * MSZ + colS) = v;
      }
    }
  }
  #undef STAGE
  #undef COMPUTE
}

// ---------------- fallback (round-1 kernel, used only if ws too small) ----------------
__global__ __launch_bounds__(256, 2)
void rbf_mfma_kernel(const float* __restrict__ X, const float* __restrict__ Y,
                     float* __restrict__ Out) {
  __shared__ unsigned short As[BM * BK];
  __shared__ unsigned short Bs[BN * BK];
  __shared__ float sx2[BM];
  __shared__ float sy2[BN];
  int bid = blockIdx.x;
  int cpx = gridDim.x >> 3;
  int swz = (bid & 7) * cpx + (bid >> 3);
  int bm = swz >> 6, bn = swz & 63;
  int rowBase = bm * BM, colBase = bn * BN;
  int tid = threadIdx.x;
  int l = tid & 63;
  int w = tid >> 6;
  int wr = w >> 1, wc = w & 1;
  f32x4 acc[4][4] = {};
  float assq[4] = {0.f,0.f,0.f,0.f};
  float bssq[4] = {0.f,0.f,0.f,0.f};
  for (int ks = 0; ks < D_DIM / BK; ++ks) {
    if (ks) __syncthreads();
    #pragma unroll
    for (int p = 0; p < 4; ++p) {
      int c = tid + 256 * p;
      int r = c >> 3;
      int kc = c & 7;
      const float* gx = X + (size_t)(rowBase + r) * D_DIM + ks * BK + kc * 8;
      const float* gy = Y + (size_t)(colBase + r) * D_DIM + ks * BK + kc * 8;
      f32x4 xa = *(const f32x4*)gx;
      f32x4 xb = *(const f32x4*)(gx + 4);
      f32x4 ya = *(const f32x4*)gy;
      f32x4 yb = *(const f32x4*)(gy + 4);
      #pragma unroll
      for (int j = 0; j < 4; ++j) {
        assq[p] += xa[j]*xa[j] + xb[j]*xb[j];
        bssq[p] += ya[j]*ya[j] + yb[j]*yb[j];
      }
      union { bf16x8 v; unsigned short u[8]; } pa, pb;
      #pragma unroll
      for (int j = 0; j < 4; ++j) {
        pa.u[j] = f2bf(xa[j]);  pa.u[j+4] = f2bf(xb[j]);
        pb.u[j] = f2bf(ya[j]);  pb.u[j+4] = f2bf(yb[j]);
      }
      int boff = (r * (BK*2) + kc * 16) ^ ((r & 7) << 4);
      *(bf16x8*)((char*)As + boff) = pa.v;
      *(bf16x8*)((char*)Bs + boff) = pb.v;
    }
    __syncthreads();
    #pragma unroll
    for (int kk = 0; kk < 2; ++kk) {
      bf16x8 af[4], bfv[4];
      #pragma unroll
      for (int i = 0; i < 4; ++i) {
        int ra = wr*64 + i*16 + (l & 15);
        int offa = (ra * (BK*2) + kk*64 + (l >> 4) * 16) ^ ((ra & 7) << 4);
        af[i] = *(bf16x8*)((char*)As + offa);
        int rb = wc*64 + i*16 + (l & 15);
        int offb = (rb * (BK*2) + kk*64 + (l >> 4) * 16) ^ ((rb & 7) << 4);
        bfv[i] = *(bf16x8*)((char*)Bs + offb);
      }
      #pragma unroll
      for (int i = 0; i < 4; ++i)
        #pragma unroll
        for (int j = 0; j < 4; ++j)
          acc[i][j] = __builtin_amdgcn_mfma_f32_16x16x32_bf16(af[i], bfv[j], acc[i][j], 0, 0, 0);
    }
  }
  #pragma unroll
  for (int p = 0; p < 4; ++p) {
    float a = assq[p], b = bssq[p];
    a += __shfl_xor(a, 1); b += __shfl_xor(b, 1);
    a += __shfl_xor(a, 2); b += __shfl_xor(b, 2);
    a += __shfl_xor(a, 4); b += __shfl_xor(b, 4);
    if ((tid & 7) == 0) {
      int r = (tid >> 3) + 32 * p;
      sx2[r] = a;
      sy2[r] = b;
    }
  }
  __syncthreads();
  #pragma unroll
  for (int i = 0; i < 4; ++i)
    #pragma unroll
    for (int j = 0; j < 4; ++j)
      #pragma unroll
      for (int q = 0; q < 4; ++q) {
        int rn = wr*64 + i*16 + (l >> 4) * 4 + q;
        int cm = wc*64 + j*16 + (l & 15);
        float d2 = sx2[rn] + sy2[cm] - 2.0f * acc[i][j][q];
        Out[(size_t)(rowBase + rn) * MSZ + (colBase + cm)] = __expf(-fmaxf(d2, 0.0f));
      }
}

extern "C" void kernel_launch(void* const* d_in, const int* in_sizes, int n_in,
                              void* d_out, int out_size, void* d_ws, size_t ws_size,
                              hipStream_t stream) {
  const float* X = (const float*)d_in[0];
  const float* Y = (const float*)d_in[1];
  float* Out = (float*)d_out;
  const size_t NEED = (size_t)MSZ * D_DIM * 2 * 2 + (size_t)MSZ * 4 * 2;  // Xb+Yb+x2+y2
  if (ws_size >= NEED) {
    unsigned short* Xb = (unsigned short*)d_ws;
    unsigned short* Yb = Xb + (size_t)MSZ * D_DIM;
    float* x2 = (float*)(Yb + (size_t)MSZ * D_DIM);
    float* y2 = x2 + MSZ;
    prep_kernel<<<dim3(4096), dim3(256), 0, stream>>>(X, Y, Xb, Yb, x2, y2);
    rbf_main<<<dim3(64 * 64), dim3(256), 0, stream>>>(Xb, Yb, x2, y2, Out);
  } else {
    rbf_mfma_kernel<<<dim3(64 * 64), dim3(256), 0, stream>>>(X, Y, Out);
  }
}

// Round 6
// 69.412 us; speedup vs baseline: 1.2452x; 1.2452x over previous
//
#include <hip/hip_runtime.h>
#include <hip/hip_bf16.h>

typedef __attribute__((ext_vector_type(4))) float f32x4;
typedef __attribute__((ext_vector_type(8))) short bf16x8;
typedef __attribute__((ext_vector_type(16))) float f32x16;
typedef long i64t;

#define MSZ 8192
#define D_DIM 256
#define BM 128
#define BN 128
#define NTILES 8

#define GLOAD_LDS(g, s) __builtin_amdgcn_global_load_lds( \
    (const __attribute__((address_space(1))) unsigned int*)(g), \
    (__attribute__((address_space(3))) unsigned int*)(s), 16, 0, 0)

__device__ __forceinline__ unsigned short f2bf(float f) {
  __hip_bfloat16 h = __float2bfloat16(f);
  unsigned short u; __builtin_memcpy(&u, &h, 2); return u;
}

// ---------------- pass 1: fp32 -> fp8(e4m3) copies + exact fp32 row norms ----------------
__global__ __launch_bounds__(256)
void prep_fp8(const float* __restrict__ X, const float* __restrict__ Y,
              unsigned char* __restrict__ Xq, unsigned char* __restrict__ Yq,
              float* __restrict__ x2, float* __restrict__ y2) {
  int gw = (blockIdx.x * 256 + threadIdx.x) >> 6;   // one wave per row; 16384 waves exactly
  int l = threadIdx.x & 63;
  int row = gw & (MSZ - 1);
  const float* src = (gw < MSZ ? X : Y) + (size_t)row * D_DIM + l * 4;
  f32x4 v = *(const f32x4*)src;
  float ss = v[0]*v[0] + v[1]*v[1] + v[2]*v[2] + v[3]*v[3];
  // pack 4 floats -> 4 OCP e4m3 bytes (values ~N(0,1): far from sat range +-448)
  int p = __builtin_amdgcn_cvt_pk_fp8_f32(v[0], v[1], 0, false);
  p = __builtin_amdgcn_cvt_pk_fp8_f32(v[2], v[3], p, true);
  unsigned char* dst = (gw < MSZ ? Xq : Yq) + (size_t)row * D_DIM + l * 4;
  *(unsigned int*)dst = (unsigned int)p;
  #pragma unroll
  for (int m = 1; m < 64; m <<= 1) ss += __shfl_xor(ss, m);
  if (l == 0) (gw < MSZ ? x2 : y2)[row] = ss;
}

// ------- pass 2: persistent 8-tile blocks, fp8 full-K LDS, store/compute pipeline -------
__global__ __launch_bounds__(256, 2)
void rbf_main(const unsigned char* __restrict__ Xq, const unsigned char* __restrict__ Yq,
              const float* __restrict__ X2, const float* __restrict__ Y2,
              float* __restrict__ Out) {
  __shared__ __align__(16) unsigned char Al[BM * D_DIM];   // 32 KB, staged once
  __shared__ __align__(16) unsigned char Bl[BN * D_DIM];   // 32 KB, per tile
  __shared__ float sx2[BM];

  int bid = blockIdx.x;                  // 512 blocks, 512 % 8 == 0 -> bijective XCD swizzle
  int swz = (bid & 7) * 64 + (bid >> 3);
  int bm = swz >> 3;                     // 64 row-panels
  int rowBase = bm * BM;
  int colBase = ((swz & 7) << 3) * BN;   // first of 8 consecutive column tiles

  int tid = threadIdx.x;
  int l = tid & 63;
  int w = tid >> 6;                      // 4 waves, 2x2 grid of 64x64 sub-tiles
  int wr = w >> 1, wc = w & 1;

  if (tid < BM) sx2[tid] = X2[rowBase + tid];

  // --- prologue staging: A panel (once) + B tile 0 + tile-0 column norms ---
  // LDS dest linear (gload_lds reqmt); XOR swizzle on the GLOBAL source granule (m173):
  // row r holds 16B-granules in order g ^ (r & 15)  ->  conflict-free ds_read_b64 later.
  #pragma unroll
  for (int q = 0; q < 8; ++q) {
    int c = tid + 256 * q;               // granule 0..2047
    int row = c >> 4, g = c & 15;
    GLOAD_LDS(Xq + (size_t)(rowBase + row) * D_DIM + (((g ^ (row & 15))) << 4), Al + c * 16);
  }
  float cy0 = Y2[colBase + wc * 64 + (l & 31)];
  float cy1 = Y2[colBase + wc * 64 + 32 + (l & 31)];
  #pragma unroll
  for (int q = 0; q < 8; ++q) {
    int c = tid + 256 * q;
    int row = c >> 4, g = c & 15;
    GLOAD_LDS(Yq + (size_t)(colBase + row) * D_DIM + (((g ^ (row & 15))) << 4), Bl + c * 16);
  }
  asm volatile("s_waitcnt lgkmcnt(0)" ::: "memory");   // sx2 ds_write visible

  const unsigned char* Abase = Al + (wr * 64 + (l & 31)) * D_DIM + ((l >> 5) << 3);
  const unsigned char* Bbase = Bl + (wc * 64 + (l & 31)) * D_DIM + ((l >> 5) << 3);
  int sk = l & 15;                       // swizzle key (row & 15 == l & 15 for our rows)
  int h4 = (l >> 5) * 4;
  int kq = (l & 31) >> 2;

  #pragma unroll 1
  for (int tt = 0; tt < NTILES; ++tt) {
    // wait for THIS tile's staging (issued before last tile's 16 stores ->
    // in-order vmcnt: vmcnt(16) drains staging+norm loads, leaves stores in flight)
    if (tt == 0) asm volatile("s_waitcnt vmcnt(0)" ::: "memory");
    else         asm volatile("s_waitcnt vmcnt(16)" ::: "memory");
    __builtin_amdgcn_s_barrier();

    float sy0 = cy0, sy1 = cy1;
    int colC = colBase;

    // --- compute: K=256 in 16 steps of v_mfma_f32_32x32x16_fp8_fp8 ---
    // A/B operand: lane l holds row (l&31), k = (l>>5)*8 + [0..8)  (8 fp8 = 1 i64)
    f32x16 acc[2][2] = {};
    #pragma unroll
    for (int kk = 0; kk < 16; ++kk) {
      int ca = (kk ^ sk) << 4;
      i64t a0 = *(const i64t*)(Abase + ca);
      i64t a1 = *(const i64t*)(Abase + 32 * D_DIM + ca);
      i64t b0 = *(const i64t*)(Bbase + ca);
      i64t b1 = *(const i64t*)(Bbase + 32 * D_DIM + ca);
      acc[0][0] = __builtin_amdgcn_mfma_f32_32x32x16_fp8_fp8(a0, b0, acc[0][0], 0, 0, 0);
      acc[0][1] = __builtin_amdgcn_mfma_f32_32x32x16_fp8_fp8(a0, b1, acc[0][1], 0, 0, 0);
      acc[1][0] = __builtin_amdgcn_mfma_f32_32x32x16_fp8_fp8(a1, b0, acc[1][0], 0, 0, 0);
      acc[1][1] = __builtin_amdgcn_mfma_f32_32x32x16_fp8_fp8(a1, b1, acc[1][1], 0, 0, 0);
    }
    __builtin_amdgcn_s_barrier();        // all waves done reading Bl -> safe to restage

    // --- issue NEXT tile's staging + norms BEFORE this tile's stores ---
    if (tt + 1 < NTILES) {
      colBase += BN;
      cy0 = Y2[colBase + wc * 64 + (l & 31)];
      cy1 = Y2[colBase + wc * 64 + 32 + (l & 31)];
      #pragma unroll
      for (int q = 0; q < 8; ++q) {
        int c = tid + 256 * q;
        int row = c >> 4, g = c & 15;
        GLOAD_LDS(Yq + (size_t)(colBase + row) * D_DIM + (((g ^ (row & 15))) << 4), Bl + c * 16);
      }
    }
    asm volatile("" ::: "memory");       // keep stores below the staging issues

    // --- epilogue: exp + in-quad 4x4 transpose -> 16 f32x4 full-line stores ---
    // C/D: col = l&31, row = (q&3) + 8*(q>>2) + 4*(l>>5)   [m74/m101]
    #pragma unroll
    for (int i = 0; i < 2; ++i) {
      #pragma unroll
      for (int j = 0; j < 2; ++j) {
        float sy = j ? sy1 : sy0;
        #pragma unroll
        for (int g = 0; g < 4; ++g) {
          int rb0 = wr * 64 + i * 32 + g * 8 + h4;
          float p0, p1, p2, p3;
          {
            float sxa = sx2[rb0 + 0], sxb = sx2[rb0 + 1];
            float sxc = sx2[rb0 + 2], sxd = sx2[rb0 + 3];
            p0 = __expf(-fmaxf(fmaf(-2.0f, acc[i][j][g * 4 + 0], sxa + sy), 0.0f));
            p1 = __expf(-fmaxf(fmaf(-2.0f, acc[i][j][g * 4 + 1], sxb + sy), 0.0f));
            p2 = __expf(-fmaxf(fmaf(-2.0f, acc[i][j][g * 4 + 2], sxc + sy), 0.0f));
            p3 = __expf(-fmaxf(fmaf(-2.0f, acc[i][j][g * 4 + 3], sxd + sy), 0.0f));
          }
          {
            float s01 = (l & 1) ? p0 : p1;
            float r01 = __shfl_xor(s01, 1);
            if (l & 1) p0 = r01; else p1 = r01;
            float s23 = (l & 1) ? p2 : p3;
            float r23 = __shfl_xor(s23, 1);
            if (l & 1) p2 = r23; else p3 = r23;
            float s02 = (l & 2) ? p0 : p2;
            float r02 = __shfl_xor(s02, 2);
            if (l & 2) p0 = r02; else p2 = r02;
            float s13 = (l & 2) ? p1 : p3;
            float r13 = __shfl_xor(s13, 2);
            if (l & 2) p1 = r13; else p3 = r13;
          }
          int rowS = rowBase + rb0 + (l & 3);
          int colS = colC + wc * 64 + j * 32 + kq * 4;
          f32x4 v; v[0] = p0; v[1] = p1; v[2] = p2; v[3] = p3;
          *(f32x4*)(Out + (size_t)rowS * MSZ + colS) = v;
        }
      }
    }
  }
}

// ---------------- fallback (round-4 bf16 kernel, used only if ws too small) ----------------
__global__ __launch_bounds__(256, 2)
void rbf_mfma_kernel(const float* __restrict__ X, const float* __restrict__ Y,
                     float* __restrict__ Out) {
  __shared__ unsigned short As[BM * 64];
  __shared__ unsigned short Bs[BN * 64];
  __shared__ float sx2[BM];
  __shared__ float sy2[BN];
  int bid = blockIdx.x;
  int cpx = gridDim.x >> 3;
  int swz = (bid & 7) * cpx + (bid >> 3);
  int bm = swz >> 6, bn = swz & 63;
  int rowBase = bm * BM, colBase = bn * BN;
  int tid = threadIdx.x;
  int l = tid & 63;
  int w = tid >> 6;
  int wr = w >> 1, wc = w & 1;
  f32x4 acc[4][4] = {};
  float assq[4] = {0.f,0.f,0.f,0.f};
  float bssq[4] = {0.f,0.f,0.f,0.f};
  for (int ks = 0; ks < D_DIM / 64; ++ks) {
    if (ks) __syncthreads();
    #pragma unroll
    for (int p = 0; p < 4; ++p) {
      int c = tid + 256 * p;
      int r = c >> 3;
      int kc = c & 7;
      const float* gx = X + (size_t)(rowBase + r) * D_DIM + ks * 64 + kc * 8;
      const float* gy = Y + (size_t)(colBase + r) * D_DIM + ks * 64 + kc * 8;
      f32x4 xa = *(const f32x4*)gx;
      f32x4 xb = *(const f32x4*)(gx + 4);
      f32x4 ya = *(const f32x4*)gy;
      f32x4 yb = *(const f32x4*)(gy + 4);
      #pragma unroll
      for (int j = 0; j < 4; ++j) {
        assq[p] += xa[j]*xa[j] + xb[j]*xb[j];
        bssq[p] += ya[j]*ya[j] + yb[j]*yb[j];
      }
      union { bf16x8 v; unsigned short u[8]; } pa, pb;
      #pragma unroll
      for (int j = 0; j < 4; ++j) {
        pa.u[j] = f2bf(xa[j]);  pa.u[j+4] = f2bf(xb[j]);
        pb.u[j] = f2bf(ya[j]);  pb.u[j+4] = f2bf(yb[j]);
      }
      int boff = (r * 128 + kc * 16) ^ ((r & 7) << 4);
      *(bf16x8*)((char*)As + boff) = pa.v;
      *(bf16x8*)((char*)Bs + boff) = pb.v;
    }
    __syncthreads();
    #pragma unroll
    for (int kk = 0; kk < 2; ++kk) {
      bf16x8 af[4], bfv[4];
      #pragma unroll
      for (int i = 0; i < 4; ++i) {
        int ra = wr*64 + i*16 + (l & 15);
        int offa = (ra * 128 + kk*64 + (l >> 4) * 16) ^ ((ra & 7) << 4);
        af[i] = *(bf16x8*)((char*)As + offa);
        int rb = wc*64 + i*16 + (l & 15);
        int offb = (rb * 128 + kk*64 + (l >> 4) * 16) ^ ((rb & 7) << 4);
        bfv[i] = *(bf16x8*)((char*)Bs + offb);
      }
      #pragma unroll
      for (int i = 0; i < 4; ++i)
        #pragma unroll
        for (int j = 0; j < 4; ++j)
          acc[i][j] = __builtin_amdgcn_mfma_f32_16x16x32_bf16(af[i], bfv[j], acc[i][j], 0, 0, 0);
    }
  }
  #pragma unroll
  for (int p = 0; p < 4; ++p) {
    float a = assq[p], b = bssq[p];
    a += __shfl_xor(a, 1); b += __shfl_xor(b, 1);
    a += __shfl_xor(a, 2); b += __shfl_xor(b, 2);
    a += __shfl_xor(a, 4); b += __shfl_xor(b, 4);
    if ((tid & 7) == 0) {
      int r = (tid >> 3) + 32 * p;
      sx2[r] = a;
      sy2[r] = b;
    }
  }
  __syncthreads();
  #pragma unroll
  for (int i = 0; i < 4; ++i)
    #pragma unroll
    for (int j = 0; j < 4; ++j)
      #pragma unroll
      for (int q = 0; q < 4; ++q) {
        int rn = wr*64 + i*16 + (l >> 4) * 4 + q;
        int cm = wc*64 + j*16 + (l & 15);
        float d2 = sx2[rn] + sy2[cm] - 2.0f * acc[i][j][q];
        Out[(size_t)(rowBase + rn) * MSZ + (colBase + cm)] = __expf(-fmaxf(d2, 0.0f));
      }
}

extern "C" void kernel_launch(void* const* d_in, const int* in_sizes, int n_in,
                              void* d_out, int out_size, void* d_ws, size_t ws_size,
                              hipStream_t stream) {
  const float* X = (const float*)d_in[0];
  const float* Y = (const float*)d_in[1];
  float* Out = (float*)d_out;
  const size_t QB = (size_t)MSZ * D_DIM;               // 2 MiB per matrix (fp8)
  const size_t NEED = QB * 2 + (size_t)MSZ * 4 * 2;    // Xq+Yq+x2+y2
  if (ws_size >= NEED) {
    unsigned char* Xq = (unsigned char*)d_ws;
    unsigned char* Yq = Xq + QB;
    float* x2 = (float*)(Yq + QB);
    float* y2 = x2 + MSZ;
    prep_fp8<<<dim3(4096), dim3(256), 0, stream>>>(X, Y, Xq, Yq, x2, y2);
    rbf_main<<<dim3(512), dim3(256), 0, stream>>>(Xq, Yq, x2, y2, Out);
  } else {
    rbf_mfma_kernel<<<dim3(64 * 64), dim3(256), 0, stream>>>(X, Y, Out);
  }
}